// Round 19
// baseline (410.928 us; speedup 1.0000x reference)
//
#include <hip/hip_runtime.h>
#include <hip/hip_cooperative_groups.h>
#include <stdint.h>

namespace cg = cooperative_groups;

#define B_ 16
#define A_ 256
#define N_ 64
#define F_ 128
#define G_ 25
#define L_ 3
#define P_ (B_*A_)      // 4096 atoms
#define CUTOFF_ 5.0f
#define OFF0_ 1.2f
#define NT_ 2048                      // filter table rows
#define DELTA_ (5.0f / 2047.0f)
#define INVD_ (2047.0f / 5.0f)
#define NWG_ (P_ / 8)                 // 512 WGs for fallback k_layer_full
#define NWGM_ 256                     // mega: 256 WGs = 1/CU guaranteed

typedef float f32x4 __attribute__((ext_vector_type(4)));
typedef __bf16 bf16x8 __attribute__((ext_vector_type(8)));

__device__ __forceinline__ uint16_t f2bf(float f) {
    union { __bf16 b; uint16_t u; } v; v.b = (__bf16)f;  // RNE hw cvt
    return v.u;
}
__device__ __forceinline__ float sspf(float x) {
    return fmaf(__log2f(1.0f + __expf(x)), 0.69314718055994531f,
                -0.69314718055994531f);
}
__device__ __forceinline__ int xcd_swizzle(int bid, int nwg) {
    const int q = nwg >> 3, r = nwg & 7;
    const int xcd = bid & 7, idx = bid >> 3;
    const int base = (xcd < r) ? xcd * (q + 1) : r * (q + 1) + (xcd - r) * q;
    return base + idx;
}

// ======================= single cooperative mega-kernel =======================
// 256 WGs x 512 thr (1 WG/CU guaranteed at <=128 VGPR). 16 atoms/WG.
__global__ __launch_bounds__(512, 2) void k_mega(
        const float* __restrict__ emb, const float* __restrict__ pos,
        const float* __restrict__ fw1, const float* __restrict__ fb1,
        const float* __restrict__ fw2, const float* __restrict__ fb2,
        const float* __restrict__ in2f, const float* __restrict__ f2ow,
        const float* __restrict__ f2o_b, const float* __restrict__ dnsw,
        const float* __restrict__ dns_b, const int* __restrict__ Z,
        const int* __restrict__ nbr, const float* __restrict__ mask,
        float* __restrict__ T, uint16_t* __restrict__ in2ft,
        uint16_t* __restrict__ f2ot, uint16_t* __restrict__ dnst,
        float* __restrict__ x, float* __restrict__ y0f,
        float* __restrict__ y1f, float* __restrict__ out)
{
    cg::grid_group grid = cg::this_grid();
    __shared__ __align__(16) unsigned char lds[17408];   // phase-shared arena

    const int t    = threadIdx.x;
    const int wave = t >> 6;
    const int lane = t & 63;

    // ---- phase 0a: transpose tail-MLP weights to bf16 [f][k] ----
    {
        const int gid = blockIdx.x * 512 + t;
        if (gid < L_ * F_ * F_) {
            const int k = gid & 127, f = (gid >> 7) & 127, l = gid >> 14;
            const size_t src = (size_t)(l * F_ + k) * F_ + f;
            in2ft[gid] = f2bf(in2f[src]);
            f2ot[gid]  = f2bf(f2ow[src]);
            dnst[gid]  = f2bf(dnsw[src]);
        }
    }
    // ---- phase 0b: build filter table (fp32 exact; 3 rows/wave) ----
    {
        float* Hs = (float*)lds + wave * 128;
        const float step = 3.8f / 24.0f;
        const float coef = -0.5f / (step * step);
        for (int rr = blockIdx.x * 8 + wave; rr < L_ * NT_; rr += NWGM_ * 8) {
            const int l = rr >> 11, rowi = rr & (NT_ - 1);
            const float r = (float)rowi * DELTA_;
            const float* w1 = fw1 + (size_t)l * G_ * F_;
            const float* w2 = fw2 + (size_t)l * F_ * F_;
            float a0 = fb1[l * F_ + lane], a1 = fb1[l * F_ + lane + 64];
#pragma unroll
            for (int k = 0; k < G_; ++k) {
                const float d = r - (OFF0_ + step * (float)k);
                const float ev = __expf(coef * d * d);
                a0 = fmaf(ev, w1[k * F_ + lane], a0);
                a1 = fmaf(ev, w1[k * F_ + lane + 64], a1);
            }
            Hs[lane] = sspf(a0);                 // same-wave LDS RAW, no barrier
            Hs[lane + 64] = sspf(a1);
            float p0 = fb2[l * F_ + lane], p1 = fb2[l * F_ + lane + 64];
            for (int k = 0; k < F_; ++k) {
                const float h = Hs[k];
                p0 = fmaf(h, w2[k * F_ + lane], p0);
                p1 = fmaf(h, w2[k * F_ + lane + 64], p1);
            }
            T[(size_t)rr * F_ + lane] = p0;
            T[(size_t)rr * F_ + lane + 64] = p1;
        }
    }
    __threadfence();
    grid.sync();

    const int row  = lane & 15;
    const int kg   = lane >> 4;
    const int fcol = wave * 16 + row;

    // ---- phase 1: x = emb[Z]; y0 = x @ in2f[0]^T (16 rows exactly) ----
    {
        float* xrow = (float*)lds;               // 16 x 136 fp32
        const int a0e = blockIdx.x * 16;
#pragma unroll
        for (int i = 0; i < 4; ++i) {
            const int idx = i * 512 + t;         // 0..2047
            const int p = a0e + (idx >> 7), f = idx & 127;
            const float v = emb[(size_t)Z[p] * F_ + f];
            x[(size_t)p * F_ + f] = v;
            xrow[(idx >> 7) * 136 + f] = v;
        }
        __syncthreads();
        f32x4 acc = {0.f, 0.f, 0.f, 0.f};
#pragma unroll
        for (int ks = 0; ks < 4; ++ks) {
            const float* xp = xrow + row * 136 + ks * 32 + kg * 8;
            float4 u0 = *(const float4*)xp;
            float4 u1 = *(const float4*)(xp + 4);
            bf16x8 a;
            a[0] = (__bf16)u0.x; a[1] = (__bf16)u0.y; a[2] = (__bf16)u0.z; a[3] = (__bf16)u0.w;
            a[4] = (__bf16)u1.x; a[5] = (__bf16)u1.y; a[6] = (__bf16)u1.z; a[7] = (__bf16)u1.w;
            bf16x8 bfr = *(const bf16x8*)(in2ft + fcol * F_ + ks * 32 + kg * 8);
            acc = __builtin_amdgcn_mfma_f32_16x16x32_bf16(a, bfr, acc, 0, 0, 0);
        }
#pragma unroll
        for (int j = 0; j < 4; ++j)
            y0f[(size_t)(a0e + kg * 4 + j) * F_ + fcol] = acc[j];
    }
    __threadfence();
    grid.sync();

    // ---- phases 2-4: three fused layers; 16 atoms/WG, wave owns 2 atoms ----
    uint16_t* abf  = (uint16_t*)lds;             // 16 x 272 B
    uint16_t* mlpH = (uint16_t*)(lds + 4352);    // 16 x 256 B swizzled
    float*    mlpX = (float*)(lds + 8448);       // 16 x 136 fp32

    const int bid = xcd_swizzle(blockIdx.x, NWGM_);
    const int a0  = bid * 16;

    // edge geometry computed ONCE for both atoms, reused across layers
    int jrowA[2]; float fcmA[2]; int i0A[2]; float wfA[2];
    unsigned long long liveA[2];
#pragma unroll
    for (int s = 0; s < 2; ++s) {
        const int atom = a0 + wave * 2 + s;
        const int molbase = atom & ~(A_ - 1);
        const int e = atom * N_ + lane;
        const int j = molbase + nbr[e];
        const float dx = pos[j * 3 + 0] - pos[atom * 3 + 0];
        const float dy = pos[j * 3 + 1] - pos[atom * 3 + 1];
        const float dz = pos[j * 3 + 2] - pos[atom * 3 + 2];
        const float r = sqrtf(dx * dx + dy * dy + dz * dz + 1e-9f);
        const float fc = (r <= CUTOFF_) ? mask[e] : 0.0f;
        const float u = fminf(r * INVD_, 2046.999f);
        jrowA[s] = j; fcmA[s] = fc;
        i0A[s] = (int)u; wfA[s] = u - (float)(int)u;
        liveA[s] = __ballot(fc != 0.0f);
    }

    float* ycur = y0f;
    float* ynxt = y1f;
    for (int l = 0; l < L_; ++l) {
        const float*    Tl    = T    + (size_t)l * NT_ * F_;
        const uint16_t* f2o_l = f2ot + (size_t)l * F_ * F_;
        const uint16_t* dns_l = dnst + (size_t)l * F_ * F_;
        const float*    ba    = f2o_b + l * F_;
        const float*    bb    = dns_b + l * F_;

        // live-edge loops (2 atoms serial); lane owns feature pair 2*lane
#pragma unroll
        for (int s = 0; s < 2; ++s) {
            unsigned long long live = liveA[s];
            float ax = 0.0f, ay = 0.0f;
            while (live) {
                const int el = __builtin_ctzll(live); live &= (live - 1);
                const int   i0e = __shfl(i0A[s], el);
                const float we  = __shfl(wfA[s], el);
                const float fce = __shfl(fcmA[s], el);
                const int   je  = __shfl(jrowA[s], el);
                const float2 ta = *(const float2*)(Tl + (size_t)i0e * F_ + lane * 2);
                const float2 tb = *(const float2*)(Tl + (size_t)(i0e + 1) * F_ + lane * 2);
                const float2 yv = *(const float2*)(ycur + (size_t)je * F_ + lane * 2);
                const float w0 = fmaf(we, tb.x - ta.x, ta.x) * fce;
                const float w1 = fmaf(we, tb.y - ta.y, ta.y) * fce;
                ax = fmaf(w0, yv.x, ax);
                ay = fmaf(w1, yv.y, ay);
            }
            *(uint32_t*)((char*)abf + (wave * 2 + s) * 272 + lane * 4) =
                (uint32_t)f2bf(ax) | ((uint32_t)f2bf(ay) << 16);
        }
        __syncthreads();   // abf complete

        // GEMM_a: H = ssp(abf @ f2o + ba), 16 rows
        {
            const float bav = ba[fcol];
            f32x4 acc = {bav, bav, bav, bav};
#pragma unroll
            for (int ks = 0; ks < 4; ++ks) {
                bf16x8 a = *(const bf16x8*)((const char*)abf + row * 272 + ks * 64 + kg * 16);
                bf16x8 bfr = *(const bf16x8*)(f2o_l + fcol * F_ + ks * 32 + kg * 8);
                acc = __builtin_amdgcn_mfma_f32_16x16x32_bf16(a, bfr, acc, 0, 0, 0);
            }
#pragma unroll
            for (int j = 0; j < 4; ++j) {
                const int rr = kg * 4 + j;
                const int byt = rr * 256 + ((fcol * 2) ^ ((rr & 7) << 4));
                *(uint16_t*)((char*)mlpH + byt) = f2bf(sspf(acc[j]));
            }
        }
        __syncthreads();   // mlpH complete

        // GEMM_b: x_new = H @ dns + bb + x, 16 rows
        {
            const float bbv = bb[fcol];
            f32x4 acc = {bbv, bbv, bbv, bbv};
#pragma unroll
            for (int ks = 0; ks < 4; ++ks) {
                const int kbyte = ks * 64 + kg * 16;
                bf16x8 a2 = *(const bf16x8*)((char*)mlpH + row * 256 + (kbyte ^ ((row & 7) << 4)));
                bf16x8 bfr = *(const bf16x8*)(dns_l + fcol * F_ + ks * 32 + kg * 8);
                acc = __builtin_amdgcn_mfma_f32_16x16x32_bf16(a2, bfr, acc, 0, 0, 0);
            }
#pragma unroll
            for (int j = 0; j < 4; ++j) {
                const int ra = kg * 4 + j;     // 0..15
                const size_t idx = (size_t)(a0 + ra) * F_ + fcol;
                const float val = acc[j] + x[idx];
                if (l < L_ - 1) {
                    x[idx] = val;
                    mlpX[ra * 136 + fcol] = val;
                } else {
                    out[idx] = val;
                }
            }
        }

        // GEMM_c: y_next = x_new @ in2f[l+1]; grid-wide handoff
        if (l < L_ - 1) {
            __syncthreads();   // mlpX complete
            const uint16_t* in2l = in2ft + (size_t)(l + 1) * F_ * F_;
            f32x4 acc = {0.f, 0.f, 0.f, 0.f};
#pragma unroll
            for (int ks = 0; ks < 4; ++ks) {
                const float* xp = mlpX + row * 136 + ks * 32 + kg * 8;
                float4 u0 = *(const float4*)xp;
                float4 u1 = *(const float4*)(xp + 4);
                bf16x8 a;
                a[0] = (__bf16)u0.x; a[1] = (__bf16)u0.y; a[2] = (__bf16)u0.z; a[3] = (__bf16)u0.w;
                a[4] = (__bf16)u1.x; a[5] = (__bf16)u1.y; a[6] = (__bf16)u1.z; a[7] = (__bf16)u1.w;
                bf16x8 bfr = *(const bf16x8*)(in2l + fcol * F_ + ks * 32 + kg * 8);
                acc = __builtin_amdgcn_mfma_f32_16x16x32_bf16(a, bfr, acc, 0, 0, 0);
            }
#pragma unroll
            for (int j = 0; j < 4; ++j)
                ynxt[(size_t)(a0 + kg * 4 + j) * F_ + fcol] = acc[j];
            __threadfence();
            grid.sync();
            float* tmp = ycur; ycur = ynxt; ynxt = tmp;
        }
    }
}

// ======================= fallback path: round-17 kernels =======================
__global__ void k_prepw(const float* __restrict__ in2f, const float* __restrict__ f2ow,
                        const float* __restrict__ dnsw,
                        uint16_t* __restrict__ in2ft, uint16_t* __restrict__ f2ot,
                        uint16_t* __restrict__ dnst) {
    int t = blockIdx.x * 256 + threadIdx.x;
    if (t < L_ * F_ * F_) {
        int k = t & (F_ - 1); int f = (t >> 7) & (F_ - 1); int l = t >> 14;
        const size_t src = (size_t)(l * F_ + k) * F_ + f;
        in2ft[t] = f2bf(in2f[src]);
        f2ot[t]  = f2bf(f2ow[src]);
        dnst[t]  = f2bf(dnsw[src]);
    }
}

__global__ __launch_bounds__(256) void k_build(
        const float* __restrict__ fw1, const float* __restrict__ fb1,
        const float* __restrict__ fw2, const float* __restrict__ fb2,
        float* __restrict__ T)
{
    const int l = blockIdx.x >> 7;
    const int rbase = (blockIdx.x & 127) * 16;
    const int c = threadIdx.x & 127;
    const int h = threadIdx.x >> 7;
    __shared__ float H_s[2][128];
    const float* w1 = fw1 + (size_t)l * G_ * F_;
    const float* w2 = fw2 + (size_t)l * F_ * F_;
    const float b1v = fb1[l * F_ + c];
    const float b2v = fb2[l * F_ + c];
    float w1c[G_];
#pragma unroll
    for (int k = 0; k < G_; ++k) w1c[k] = w1[k * F_ + c];
    const float step = 3.8f / 24.0f;
    const float coef = -0.5f / (step * step);
    for (int it = 0; it < 8; ++it) {
        const int row = rbase + it * 2 + h;
        const float r = (float)row * DELTA_;
        float a = b1v;
#pragma unroll
        for (int k = 0; k < G_; ++k) {
            const float d = r - (OFF0_ + step * (float)k);
            a = fmaf(__expf(coef * d * d), w1c[k], a);
        }
        H_s[h][c] = sspf(a);
        __syncthreads();
        float phi = b2v;
        for (int k = 0; k < F_; ++k)
            phi = fmaf(H_s[h][k], w2[k * F_ + c], phi);
        T[((size_t)l * NT_ + row) * F_ + c] = phi;
        __syncthreads();
    }
}

__global__ __launch_bounds__(256) void k_embed_proj(
        const float* __restrict__ emb, const int* __restrict__ Z,
        const uint16_t* __restrict__ in2ft0,
        float* __restrict__ x, float* __restrict__ y)
{
    const int wave = threadIdx.x >> 6;
    const int lane = threadIdx.x & 63;
    const int row  = lane & 15;
    const int kg   = lane >> 4;
    const int rb   = blockIdx.x * 64 + wave * 16;
    const int zr   = Z[rb + row];

    f32x4 acc[8];
#pragma unroll
    for (int nt = 0; nt < 8; ++nt) acc[nt] = (f32x4){0.f, 0.f, 0.f, 0.f};
#pragma unroll
    for (int ks = 0; ks < 4; ++ks) {
        const float* ep = emb + (size_t)zr * F_ + ks * 32 + kg * 8;
        float4 e0 = *(const float4*)ep;
        float4 e1 = *(const float4*)(ep + 4);
        bf16x8 a;
        a[0] = (__bf16)e0.x; a[1] = (__bf16)e0.y; a[2] = (__bf16)e0.z; a[3] = (__bf16)e0.w;
        a[4] = (__bf16)e1.x; a[5] = (__bf16)e1.y; a[6] = (__bf16)e1.z; a[7] = (__bf16)e1.w;
#pragma unroll
        for (int nt = 0; nt < 8; ++nt) {
            bf16x8 bfr = *(const bf16x8*)(in2ft0 + (nt * 16 + row) * F_ + ks * 32 + kg * 8);
            acc[nt] = __builtin_amdgcn_mfma_f32_16x16x32_bf16(a, bfr, acc[nt], 0, 0, 0);
        }
    }
#pragma unroll
    for (int nt = 0; nt < 8; ++nt)
#pragma unroll
        for (int j = 0; j < 4; ++j)
            y[(size_t)(rb + kg * 4 + j) * F_ + nt * 16 + row] = acc[nt][j];

    const int rb0 = blockIdx.x * 64;
#pragma unroll
    for (int i = 0; i < 32; ++i) {
        int idx = i * 256 + threadIdx.x;
        int p = rb0 + (idx >> 7), f = idx & 127;
        x[(size_t)p * F_ + f] = emb[(size_t)Z[p] * F_ + f];
    }
}

__global__ __launch_bounds__(512) void k_layer_full(
        const float* __restrict__ pos, const int* __restrict__ nbr,
        const float* __restrict__ mask, const float* __restrict__ y,
        const float* __restrict__ Tl,
        const uint16_t* __restrict__ f2ot, const float* __restrict__ ba,
        const uint16_t* __restrict__ dnst, const float* __restrict__ bb,
        const uint16_t* __restrict__ in2ftN,
        float* __restrict__ x, float* __restrict__ yout, float* __restrict__ out)
{
    __shared__ __align__(16) uint16_t abf[8 * 136];
    __shared__ __align__(16) uint16_t mlpH[16 * 128];
    __shared__ __align__(16) float    mlpX[8 * 136];

    const int wave = threadIdx.x >> 6;
    const int lane = threadIdx.x & 63;
    const int bid  = xcd_swizzle(blockIdx.x, NWG_);
    const int a0   = bid * 8;
    const int atom = a0 + wave;
    const int molbase = atom & ~(A_ - 1);

    const int e = atom * N_ + lane;
    const int jrow = molbase + nbr[e];
    const float dx = pos[jrow * 3 + 0] - pos[atom * 3 + 0];
    const float dy = pos[jrow * 3 + 1] - pos[atom * 3 + 1];
    const float dz = pos[jrow * 3 + 2] - pos[atom * 3 + 2];
    const float r = sqrtf(dx * dx + dy * dy + dz * dz + 1e-9f);
    const float fcm = (r <= CUTOFF_) ? mask[e] : 0.0f;
    float u = fminf(r * INVD_, 2046.999f);
    const int i0 = (int)u;
    const float wf = u - (float)i0;

    unsigned long long live = __ballot(fcm != 0.0f);
    float ax = 0.0f, ay = 0.0f;
    while (live) {
        const int el = __builtin_ctzll(live); live &= (live - 1);
        const int   i0e = __shfl(i0, el);
        const float we  = __shfl(wf, el);
        const float fce = __shfl(fcm, el);
        const int   je  = __shfl(jrow, el);
        const float2 ta = *(const float2*)(Tl + (size_t)i0e * F_ + lane * 2);
        const float2 tb = *(const float2*)(Tl + (size_t)(i0e + 1) * F_ + lane * 2);
        const float2 yv = *(const float2*)(y + (size_t)je * F_ + lane * 2);
        const float w0 = fmaf(we, tb.x - ta.x, ta.x) * fce;
        const float w1 = fmaf(we, tb.y - ta.y, ta.y) * fce;
        ax = fmaf(w0, yv.x, ax);
        ay = fmaf(w1, yv.y, ay);
    }
    *(uint32_t*)((char*)abf + wave * 272 + lane * 4) =
        (uint32_t)f2bf(ax) | ((uint32_t)f2bf(ay) << 16);
    __syncthreads();

    const int row  = lane & 15;
    const int kg   = lane >> 4;
    const int fcol = wave * 16 + row;
    const int r8   = row & 7;

    {
        const float bav = ba[fcol];
        f32x4 acc = {bav, bav, bav, bav};
#pragma unroll
        for (int ks = 0; ks < 4; ++ks) {
            bf16x8 a = *(const bf16x8*)((const char*)abf + r8 * 272 + ks * 64 + kg * 16);
            bf16x8 bfr = *(const bf16x8*)(f2ot + fcol * F_ + ks * 32 + kg * 8);
            acc = __builtin_amdgcn_mfma_f32_16x16x32_bf16(a, bfr, acc, 0, 0, 0);
        }
#pragma unroll
        for (int j = 0; j < 4; ++j) {
            const int rr = kg * 4 + j;
            const int byt = rr * 256 + ((fcol * 2) ^ ((rr & 7) << 4));
            *(uint16_t*)((char*)mlpH + byt) = f2bf(sspf(acc[j]));
        }
    }
    __syncthreads();

    {
        const float bbv = bb[fcol];
        f32x4 acc = {bbv, bbv, bbv, bbv};
#pragma unroll
        for (int ks = 0; ks < 4; ++ks) {
            const int kbyte = ks * 64 + kg * 16;
            bf16x8 a2 = *(const bf16x8*)((char*)mlpH + row * 256 + (kbyte ^ ((row & 7) << 4)));
            bf16x8 bfr = *(const bf16x8*)(dnst + fcol * F_ + ks * 32 + kg * 8);
            acc = __builtin_amdgcn_mfma_f32_16x16x32_bf16(a2, bfr, acc, 0, 0, 0);
        }
        if (kg < 2) {
#pragma unroll
            for (int j = 0; j < 4; ++j) {
                const int ra = kg * 4 + j;
                const size_t idx = (size_t)(a0 + ra) * F_ + fcol;
                const float val = acc[j] + x[idx];
                x[idx] = val;
                mlpX[ra * 136 + fcol] = val;
                if (out) out[idx] = val;
            }
        }
    }

    if (in2ftN) {
        __syncthreads();
        f32x4 acc = {0.f, 0.f, 0.f, 0.f};
#pragma unroll
        for (int ks = 0; ks < 4; ++ks) {
            const float* xp = mlpX + r8 * 136 + ks * 32 + kg * 8;
            float4 u0 = *(const float4*)xp;
            float4 u1 = *(const float4*)(xp + 4);
            bf16x8 a;
            a[0] = (__bf16)u0.x; a[1] = (__bf16)u0.y; a[2] = (__bf16)u0.z; a[3] = (__bf16)u0.w;
            a[4] = (__bf16)u1.x; a[5] = (__bf16)u1.y; a[6] = (__bf16)u1.z; a[7] = (__bf16)u1.w;
            bf16x8 bfr = *(const bf16x8*)(in2ftN + fcol * F_ + ks * 32 + kg * 8);
            acc = __builtin_amdgcn_mfma_f32_16x16x32_bf16(a, bfr, acc, 0, 0, 0);
        }
        if (kg < 2) {
#pragma unroll
            for (int j = 0; j < 4; ++j)
                yout[(size_t)(a0 + kg * 4 + j) * F_ + fcol] = acc[j];
        }
    }
}

extern "C" void kernel_launch(void* const* d_in, const int* in_sizes, int n_in,
                              void* d_out, int out_size, void* d_ws, size_t ws_size,
                              hipStream_t stream) {
    const float* emb   = (const float*)d_in[0];
    const float* pos   = (const float*)d_in[1];
    const float* fw1   = (const float*)d_in[2];
    const float* fb1   = (const float*)d_in[3];
    const float* fw2   = (const float*)d_in[4];
    const float* fb2   = (const float*)d_in[5];
    const float* in2f  = (const float*)d_in[6];
    const float* f2o_w = (const float*)d_in[7];
    const float* f2o_b = (const float*)d_in[8];
    const float* dns_w = (const float*)d_in[9];
    const float* dns_b = (const float*)d_in[10];
    const int*   Z     = (const int*)d_in[11];
    const int*   nbrs  = (const int*)d_in[12];
    const float* mask  = (const float*)d_in[13];

    char* ws = (char*)d_ws;
    size_t off = 0;
    auto alloc = [&](size_t bytes) {
        char* p = ws + off; off += (bytes + 255) & ~(size_t)255; return p;
    };
    float*    x     = (float*)   alloc((size_t)P_ * F_ * 4);
    float*    y0    = (float*)   alloc((size_t)P_ * F_ * 4);
    float*    y1    = (float*)   alloc((size_t)P_ * F_ * 4);
    float*    T     = (float*)   alloc((size_t)L_ * NT_ * F_ * 4);   // 3 MB
    uint16_t* in2ft = (uint16_t*)alloc((size_t)L_ * F_ * F_ * 2);
    uint16_t* f2ot  = (uint16_t*)alloc((size_t)L_ * F_ * F_ * 2);
    uint16_t* dnst  = (uint16_t*)alloc((size_t)L_ * F_ * F_ * 2);
    float*    outp  = (float*)d_out;

    void* args[] = {
        (void*)&emb, (void*)&pos, (void*)&fw1, (void*)&fb1, (void*)&fw2,
        (void*)&fb2, (void*)&in2f, (void*)&f2o_w, (void*)&f2o_b,
        (void*)&dns_w, (void*)&dns_b, (void*)&Z, (void*)&nbrs, (void*)&mask,
        (void*)&T, (void*)&in2ft, (void*)&f2ot, (void*)&dnst,
        (void*)&x, (void*)&y0, (void*)&y1, (void*)&outp
    };
    hipError_t err = hipLaunchCooperativeKernel((void*)k_mega, dim3(NWGM_),
                                                dim3(512), args, 0, stream);
    if (err != hipSuccess) {
        (void)hipGetLastError();   // clear sticky error, take fallback path
        k_prepw<<<192, 256, 0, stream>>>(in2f, f2o_w, dns_w, in2ft, f2ot, dnst);
        k_build<<<L_ * 128, 256, 0, stream>>>(fw1, fb1, fw2, fb2, T);
        k_embed_proj<<<P_ / 64, 256, 0, stream>>>(emb, Z, in2ft, x, y0);
        float* ycur = y0;
        float* ynxt = y1;
        for (int l = 0; l < L_; ++l) {
            k_layer_full<<<NWG_, 512, 0, stream>>>(
                pos, nbrs, mask, ycur,
                T + (size_t)l * NT_ * F_,
                f2ot + (size_t)l * F_ * F_, f2o_b + (size_t)l * F_,
                dnst + (size_t)l * F_ * F_, dns_b + (size_t)l * F_,
                (l < L_ - 1) ? (in2ft + (size_t)(l + 1) * F_ * F_) : nullptr,
                x, ynxt, (l == L_ - 1) ? (float*)d_out : nullptr);
            float* t = ycur; ycur = ynxt; ynxt = t;
        }
    }
}